// Round 4
// baseline (97.456 us; speedup 1.0000x reference)
//
#include <hip/hip_runtime.h>
#include <math.h>

#define BB 8
#define TT 256
#define DD 12
#define HH 4
#define HDIM 3
#define KSPLIT 8
#define KCHUNK (TT / KSPLIT)   // 32 keys per block
#define MASK_NEG -3.0e38f

// ---------------------------------------------------------------------------
// Kernel 1: attention partials. Grid = B*H*KSPLIT = 256 blocks (1 per CU)
// x 256 threads. Block = (b, h, key-eighth). Thread t = query token t.
// Threads 0..31 produce K/V for the block's 32 keys into LDS.
// Softmax WITHOUT max-subtraction (scores are O(8); exp-partials combine
// linearly across key-splits) -> inner loop is 4 independent fma chains.
// 32 iterations per thread. Partial: float4{sum, a0, a1, a2}.
// ---------------------------------------------------------------------------
__global__ __launch_bounds__(TT) void attn_partial_kernel(
    const float* __restrict__ x,     // [B,T,D]
    const float* __restrict__ wi,    // [3D,D]
    const float* __restrict__ bi,    // [3D]
    const int*   __restrict__ mask,  // [B,T]
    float4* __restrict__ part)       // [B*T, H, KSPLIT]
{
    const int bh = blockIdx.x >> 3;   // b*HH + h
    const int kq = blockIdx.x & 7;    // key eighth
    const int b = bh / HH;
    const int h = bh % HH;
    const int t = threadIdx.x;

    __shared__ float4 kk4[KCHUNK];   // {k0,k1,k2, maskbias}
    __shared__ float4 vv4[KCHUNK];   // {v0,v1,v2, 0}

    // ---- K/V for this block's 32 keys (threads 0..31) ----
    if (t < KCHUNK) {
        const int key = kq * KCHUNK + t;
        const float4* kr4 = (const float4*)(x + (b * TT + key) * DD);
        const float4 c0 = kr4[0], c1 = kr4[1], c2 = kr4[2];
        const float kvv[DD] = {c0.x, c0.y, c0.z, c0.w, c1.x, c1.y, c1.z, c1.w,
                               c2.x, c2.y, c2.z, c2.w};
        float kx[HDIM], vx[HDIM];
#pragma unroll
        for (int d = 0; d < HDIM; ++d) {
            const int rk = DD + h * HDIM + d;
            const int rv = 2 * DD + h * HDIM + d;
            float ak = bi[rk], av = bi[rv];
#pragma unroll
            for (int j = 0; j < DD; ++j) {
                ak = fmaf(wi[rk * DD + j], kvv[j], ak);
                av = fmaf(wi[rv * DD + j], kvv[j], av);
            }
            kx[d] = ak; vx[d] = av;
        }
        const float mb = (mask[b * TT + key] != 0) ? MASK_NEG : 0.0f;
        kk4[t] = make_float4(kx[0], kx[1], kx[2], mb);
        vv4[t] = make_float4(vx[0], vx[1], vx[2], 0.0f);
    }

    // ---- q for this thread's query (pre-scaled by 1/sqrt(hd)) ----
    const float4* xr4 = (const float4*)(x + (b * TT + t) * DD);
    const float4 p0 = xr4[0], p1 = xr4[1], p2 = xr4[2];
    const float xv[DD] = {p0.x, p0.y, p0.z, p0.w, p1.x, p1.y, p1.z, p1.w,
                          p2.x, p2.y, p2.z, p2.w};
    const float scale = 0.57735026918962576f; // 1/sqrt(3)
    float qs[HDIM];
#pragma unroll
    for (int d = 0; d < HDIM; ++d) {
        const int rq = h * HDIM + d;
        float a = bi[rq];
#pragma unroll
        for (int j = 0; j < DD; ++j) a = fmaf(wi[rq * DD + j], xv[j], a);
        qs[d] = a * scale;
    }
    __syncthreads();

    // ---- 32-key partial accumulation: 4 independent fma chains ----
    float sum = 0.f, a0 = 0.f, a1 = 0.f, a2 = 0.f;
#pragma unroll
    for (int k = 0; k < KCHUNK; ++k) {
        const float4 kk = kk4[k];
        const float4 vv = vv4[k];
        const float s = fmaf(qs[0], kk.x, fmaf(qs[1], kk.y, fmaf(qs[2], kk.z, kk.w)));
        const float e = __expf(s);
        sum += e;
        a0 = fmaf(e, vv.x, a0);
        a1 = fmaf(e, vv.y, a1);
        a2 = fmaf(e, vv.z, a2);
    }
    part[((b * TT + t) * HH + h) * KSPLIT + kq] = make_float4(sum, a0, a1, a2);
}

// ---------------------------------------------------------------------------
// Closed-form measurement of the n_layers=2 circuit (one CNOT ring):
//   <Z_w> = prod_{j=0..w} z_j (w>=1),  <Z_0> = prod_{j=1..11} z_j
// ---------------------------------------------------------------------------
__device__ __forceinline__ void ring_measure(const float* z, float* outp)
{
    float pref = 1.0f;
#pragma unroll
    for (int j = 0; j < DD; ++j) { pref *= z[j]; outp[j] = pref; }
    float suf = 1.0f;
#pragma unroll
    for (int j = 1; j < DD; ++j) suf *= z[j];
    outp[0] = suf;
}

__device__ __forceinline__ void layer_norm(float* v, const float* __restrict__ g,
                                           const float* __restrict__ b)
{
    float mean = 0.f;
#pragma unroll
    for (int j = 0; j < DD; ++j) mean += v[j];
    mean *= (1.0f / DD);
    float var = 0.f;
#pragma unroll
    for (int j = 0; j < DD; ++j) { float d = v[j] - mean; var = fmaf(d, d, var); }
    var *= (1.0f / DD);
    const float r = rsqrtf(var + 1e-5f);
#pragma unroll
    for (int j = 0; j < DD; ++j) v[j] = (v[j] - mean) * r * g[j] + b[j];
}

// ---------------------------------------------------------------------------
// Kernel 2: per-token tail. Merge KSPLIT attention partials -> out-proj ->
// closed-form attn circuit -> LN1 -> lin1 -> closed-form FFN circuit ->
// lin2+ReLU -> LN2.
// ---------------------------------------------------------------------------
__global__ __launch_bounds__(64) void fused_tail_kernel(
    const float* __restrict__ x,
    const float4* __restrict__ part,  // [B*T, H, KSPLIT]
    const float* __restrict__ wo, const float* __restrict__ bo,
    const float* __restrict__ th_a,
    const float* __restrict__ w1, const float* __restrict__ b1,
    const float* __restrict__ th_f,
    const float* __restrict__ w2, const float* __restrict__ b2,
    const float* __restrict__ g1, const float* __restrict__ be1,
    const float* __restrict__ g2, const float* __restrict__ be2,
    float* __restrict__ out)
{
    const int n = blockIdx.x * blockDim.x + threadIdx.x;
    if (n >= BB * TT) return;

    // ---- merge attention partials: pairwise linear combine, 1 rcp/head ----
    float hv[DD];
    const float4* pp = part + n * HH * KSPLIT;
#pragma unroll
    for (int h = 0; h < HH; ++h) {
        float s = 0.f, a0 = 0.f, a1 = 0.f, a2 = 0.f;
        float s2 = 0.f, b0 = 0.f, b1v = 0.f, b2v = 0.f;
#pragma unroll
        for (int q = 0; q < KSPLIT; q += 2) {
            const float4 pa = pp[h * KSPLIT + q];
            const float4 pb = pp[h * KSPLIT + q + 1];
            s  += pa.x; a0 += pa.y; a1 += pa.z; a2 += pa.w;
            s2 += pb.x; b0 += pb.y; b1v += pb.z; b2v += pb.w;
        }
        const float inv = __builtin_amdgcn_rcpf(s + s2);
        hv[h * HDIM + 0] = (a0 + b0) * inv;
        hv[h * HDIM + 1] = (a1 + b1v) * inv;
        hv[h * HDIM + 2] = (a2 + b2v) * inv;
    }

    // attention out-projection
    float ac[DD];
#pragma unroll
    for (int d = 0; d < DD; ++d) {
        float a = bo[d];
#pragma unroll
        for (int j = 0; j < DD; ++j) a = fmaf(wo[d * DD + j], hv[j], a);
        ac[d] = a;
    }

    // quantum attention circuit: RX(x)·RX(theta) => z = cos(x+theta)
    float z[DD], aq[DD];
#pragma unroll
    for (int j = 0; j < DD; ++j) z[j] = __cosf(ac[j] + th_a[j]);
    ring_measure(z, aq);

    // x1 = LN1(x + attn_q)
    const float4* xr4 = (const float4*)(x + n * DD);
    const float4 x0 = xr4[0], x1q = xr4[1], x2q = xr4[2];
    float x1[DD] = {x0.x, x0.y, x0.z, x0.w, x1q.x, x1q.y, x1q.z, x1q.w,
                    x2q.x, x2q.y, x2q.z, x2q.w};
#pragma unroll
    for (int j = 0; j < DD; ++j) x1[j] += aq[j];
    layer_norm(x1, g1, be1);

    // q_in = x1 @ lin1_w^T + lin1_b
    float qi[DD];
#pragma unroll
    for (int d = 0; d < DD; ++d) {
        float a = b1[d];
#pragma unroll
        for (int j = 0; j < DD; ++j) a = fmaf(w1[d * DD + j], x1[j], a);
        qi[d] = a;
    }

    // quantum FFN circuit: RY(theta)·RX(x) => z = cos(theta)*cos(x)
    float fq[DD];
#pragma unroll
    for (int j = 0; j < DD; ++j) z[j] = __cosf(th_f[j]) * __cosf(qi[j]);
    ring_measure(z, fq);

    // ffn_out = relu(fq @ lin2_w^T + lin2_b); y = x1 + ffn_out; LN2
    float y[DD];
#pragma unroll
    for (int d = 0; d < DD; ++d) {
        float a = b2[d];
#pragma unroll
        for (int j = 0; j < DD; ++j) a = fmaf(w2[d * DD + j], fq[j], a);
        y[d] = fmaxf(a, 0.0f) + x1[d];
    }
    layer_norm(y, g2, be2);

    float4* or4 = (float4*)(out + n * DD);
    or4[0] = make_float4(y[0], y[1], y[2],  y[3]);
    or4[1] = make_float4(y[4], y[5], y[6],  y[7]);
    or4[2] = make_float4(y[8], y[9], y[10], y[11]);
}

extern "C" void kernel_launch(void* const* d_in, const int* in_sizes, int n_in,
                              void* d_out, int out_size, void* d_ws, size_t ws_size,
                              hipStream_t stream)
{
    const float* x    = (const float*)d_in[0];
    const float* wi   = (const float*)d_in[1];   // in_proj_w [36,12]
    const float* bi   = (const float*)d_in[2];   // in_proj_b [36]
    const float* wo   = (const float*)d_in[3];   // out_proj_w [12,12]
    const float* bo   = (const float*)d_in[4];   // out_proj_b [12]
    const float* tha  = (const float*)d_in[5];   // attn_theta [12]
    const float* w1   = (const float*)d_in[6];   // lin1_w [12,12]
    const float* b1   = (const float*)d_in[7];   // lin1_b [12]
    const float* thf  = (const float*)d_in[8];   // ffn_theta [12]
    const float* w2   = (const float*)d_in[9];   // lin2_w [12,12]
    const float* b2   = (const float*)d_in[10];  // lin2_b [12]
    const float* g1   = (const float*)d_in[11];  // ln1_g
    const float* be1  = (const float*)d_in[12];  // ln1_b
    const float* g2   = (const float*)d_in[13];  // ln2_g
    const float* be2  = (const float*)d_in[14];  // ln2_b
    const int*   mask = (const int*)d_in[15];    // mask [8,256]
    float* out = (float*)d_out;
    float4* part = (float4*)d_ws;                // [B*T, H, KSPLIT] = 1 MB

    attn_partial_kernel<<<BB * HH * KSPLIT, TT, 0, stream>>>(x, wi, bi, mask, part);
    fused_tail_kernel<<<(BB * TT + 63) / 64, 64, 0, stream>>>(
        x, part, wo, bo, tha, w1, b1, thf, w2, b2, g1, be1, g2, be2, out);
}

// Round 5
// 93.475 us; speedup vs baseline: 1.0426x; 1.0426x over previous
//
#include <hip/hip_runtime.h>
#include <math.h>

#define BB 8
#define TT 256
#define DD 12
#define HH 4
#define HDIM 3
#define KSPLIT 4
#define KCHUNK (TT / KSPLIT)   // 64 keys per block
#define MASK_NEG -3.0e38f

// ---------------------------------------------------------------------------
// Kernel 1: attention partials. Grid = B*H*KSPLIT blocks x 256 threads.
// Block = (b, h, key-quarter). Thread t = query token t (all 256 queries).
// Threads 0..63 additionally produce K/V for the block's 64 keys into LDS.
// Softmax WITHOUT max-subtraction (scores are O(8); exp-partials combine
// linearly across key-splits) -> inner loop is 4 independent fma chains,
// no serial online-softmax dependency. 64 iterations per thread.
// Partials: float4{sum, a0, a1, a2} at part[((b*T+t)*H + h)*KSPLIT + kq].
// KSPLIT=4 is the measured sweet spot: KSPLIT=8 regressed (per-block
// startup no longer amortized; 2x partial traffic).
// ---------------------------------------------------------------------------
__global__ __launch_bounds__(TT) void attn_partial_kernel(
    const float* __restrict__ x,     // [B,T,D]
    const float* __restrict__ wi,    // [3D,D]
    const float* __restrict__ bi,    // [3D]
    const int*   __restrict__ mask,  // [B,T]
    float4* __restrict__ part)       // [B*T, H, KSPLIT]
{
    const int bh = blockIdx.x >> 2;   // b*HH + h
    const int kq = blockIdx.x & 3;    // key quarter
    const int b = bh / HH;
    const int h = bh % HH;
    const int t = threadIdx.x;

    __shared__ float4 kk4[KCHUNK];   // {k0,k1,k2, maskbias}
    __shared__ float4 vv4[KCHUNK];   // {v0,v1,v2, 0}

    // ---- K/V for this block's 64 keys (threads 0..63) ----
    if (t < KCHUNK) {
        const int key = kq * KCHUNK + t;
        const float4* kr4 = (const float4*)(x + (b * TT + key) * DD);
        const float4 c0 = kr4[0], c1 = kr4[1], c2 = kr4[2];
        const float kvv[DD] = {c0.x, c0.y, c0.z, c0.w, c1.x, c1.y, c1.z, c1.w,
                               c2.x, c2.y, c2.z, c2.w};
        float kx[HDIM], vx[HDIM];
#pragma unroll
        for (int d = 0; d < HDIM; ++d) {
            const int rk = DD + h * HDIM + d;
            const int rv = 2 * DD + h * HDIM + d;
            float ak = bi[rk], av = bi[rv];
#pragma unroll
            for (int j = 0; j < DD; ++j) {
                ak = fmaf(wi[rk * DD + j], kvv[j], ak);
                av = fmaf(wi[rv * DD + j], kvv[j], av);
            }
            kx[d] = ak; vx[d] = av;
        }
        const float mb = (mask[b * TT + key] != 0) ? MASK_NEG : 0.0f;
        kk4[t] = make_float4(kx[0], kx[1], kx[2], mb);
        vv4[t] = make_float4(vx[0], vx[1], vx[2], 0.0f);
    }

    // ---- q for this thread's query (pre-scaled by 1/sqrt(hd)) ----
    const float4* xr4 = (const float4*)(x + (b * TT + t) * DD);
    const float4 p0 = xr4[0], p1 = xr4[1], p2 = xr4[2];
    const float xv[DD] = {p0.x, p0.y, p0.z, p0.w, p1.x, p1.y, p1.z, p1.w,
                          p2.x, p2.y, p2.z, p2.w};
    const float scale = 0.57735026918962576f; // 1/sqrt(3)
    float qs[HDIM];
#pragma unroll
    for (int d = 0; d < HDIM; ++d) {
        const int rq = h * HDIM + d;
        float a = bi[rq];
#pragma unroll
        for (int j = 0; j < DD; ++j) a = fmaf(wi[rq * DD + j], xv[j], a);
        qs[d] = a * scale;
    }
    __syncthreads();

    // ---- 64-key partial accumulation: 4 independent fma chains ----
    float sum = 0.f, a0 = 0.f, a1 = 0.f, a2 = 0.f;
#pragma unroll
    for (int k = 0; k < KCHUNK; ++k) {
        const float4 kk = kk4[k];
        const float4 vv = vv4[k];
        const float s = fmaf(qs[0], kk.x, fmaf(qs[1], kk.y, fmaf(qs[2], kk.z, kk.w)));
        const float e = __expf(s);
        sum += e;
        a0 = fmaf(e, vv.x, a0);
        a1 = fmaf(e, vv.y, a1);
        a2 = fmaf(e, vv.z, a2);
    }
    part[((b * TT + t) * HH + h) * KSPLIT + kq] = make_float4(sum, a0, a1, a2);
}

// ---------------------------------------------------------------------------
// Closed-form measurement of the n_layers=2 circuit (one CNOT ring):
//   <Z_w> = prod_{j=0..w} z_j (w>=1),  <Z_0> = prod_{j=1..11} z_j
// ---------------------------------------------------------------------------
__device__ __forceinline__ void ring_measure(const float* z, float* outp)
{
    float pref = 1.0f;
#pragma unroll
    for (int j = 0; j < DD; ++j) { pref *= z[j]; outp[j] = pref; }
    float suf = 1.0f;
#pragma unroll
    for (int j = 1; j < DD; ++j) suf *= z[j];
    outp[0] = suf;
}

__device__ __forceinline__ void layer_norm(float* v, const float* __restrict__ g,
                                           const float* __restrict__ b)
{
    float mean = 0.f;
#pragma unroll
    for (int j = 0; j < DD; ++j) mean += v[j];
    mean *= (1.0f / DD);
    float var = 0.f;
#pragma unroll
    for (int j = 0; j < DD; ++j) { float d = v[j] - mean; var = fmaf(d, d, var); }
    var *= (1.0f / DD);
    const float r = rsqrtf(var + 1e-5f);
#pragma unroll
    for (int j = 0; j < DD; ++j) v[j] = (v[j] - mean) * r * g[j] + b[j];
}

// ---------------------------------------------------------------------------
// Kernel 2: per-token tail. Merge KSPLIT attention partials -> out-proj ->
// closed-form attn circuit -> LN1 -> lin1 -> closed-form FFN circuit ->
// lin2+ReLU -> LN2.
// ---------------------------------------------------------------------------
__global__ __launch_bounds__(64) void fused_tail_kernel(
    const float* __restrict__ x,
    const float4* __restrict__ part,  // [B*T, H, KSPLIT]
    const float* __restrict__ wo, const float* __restrict__ bo,
    const float* __restrict__ th_a,
    const float* __restrict__ w1, const float* __restrict__ b1,
    const float* __restrict__ th_f,
    const float* __restrict__ w2, const float* __restrict__ b2,
    const float* __restrict__ g1, const float* __restrict__ be1,
    const float* __restrict__ g2, const float* __restrict__ be2,
    float* __restrict__ out)
{
    const int n = blockIdx.x * blockDim.x + threadIdx.x;
    if (n >= BB * TT) return;

    // ---- merge attention partials: linear combine, one divide per head ----
    float hv[DD];
    const float4* pp = part + n * HH * KSPLIT;
#pragma unroll
    for (int h = 0; h < HH; ++h) {
        const float4 q0 = pp[h * KSPLIT + 0];
        const float4 q1 = pp[h * KSPLIT + 1];
        const float4 q2 = pp[h * KSPLIT + 2];
        const float4 q3 = pp[h * KSPLIT + 3];
        const float s  = (q0.x + q1.x) + (q2.x + q3.x);
        const float inv = __builtin_amdgcn_rcpf(s);
        hv[h * HDIM + 0] = ((q0.y + q1.y) + (q2.y + q3.y)) * inv;
        hv[h * HDIM + 1] = ((q0.z + q1.z) + (q2.z + q3.z)) * inv;
        hv[h * HDIM + 2] = ((q0.w + q1.w) + (q2.w + q3.w)) * inv;
    }

    // attention out-projection
    float ac[DD];
#pragma unroll
    for (int d = 0; d < DD; ++d) {
        float a = bo[d];
#pragma unroll
        for (int j = 0; j < DD; ++j) a = fmaf(wo[d * DD + j], hv[j], a);
        ac[d] = a;
    }

    // quantum attention circuit: RX(x)·RX(theta) => z = cos(x+theta)
    float z[DD], aq[DD];
#pragma unroll
    for (int j = 0; j < DD; ++j) z[j] = __cosf(ac[j] + th_a[j]);
    ring_measure(z, aq);

    // x1 = LN1(x + attn_q)
    const float4* xr4 = (const float4*)(x + n * DD);
    const float4 x0 = xr4[0], x1q = xr4[1], x2q = xr4[2];
    float x1[DD] = {x0.x, x0.y, x0.z, x0.w, x1q.x, x1q.y, x1q.z, x1q.w,
                    x2q.x, x2q.y, x2q.z, x2q.w};
#pragma unroll
    for (int j = 0; j < DD; ++j) x1[j] += aq[j];
    layer_norm(x1, g1, be1);

    // q_in = x1 @ lin1_w^T + lin1_b
    float qi[DD];
#pragma unroll
    for (int d = 0; d < DD; ++d) {
        float a = b1[d];
#pragma unroll
        for (int j = 0; j < DD; ++j) a = fmaf(w1[d * DD + j], x1[j], a);
        qi[d] = a;
    }

    // quantum FFN circuit: RY(theta)·RX(x) => z = cos(theta)*cos(x)
    float fq[DD];
#pragma unroll
    for (int j = 0; j < DD; ++j) z[j] = __cosf(th_f[j]) * __cosf(qi[j]);
    ring_measure(z, fq);

    // ffn_out = relu(fq @ lin2_w^T + lin2_b); y = x1 + ffn_out; LN2
    float y[DD];
#pragma unroll
    for (int d = 0; d < DD; ++d) {
        float a = b2[d];
#pragma unroll
        for (int j = 0; j < DD; ++j) a = fmaf(w2[d * DD + j], fq[j], a);
        y[d] = fmaxf(a, 0.0f) + x1[d];
    }
    layer_norm(y, g2, be2);

    float4* or4 = (float4*)(out + n * DD);
    or4[0] = make_float4(y[0], y[1], y[2],  y[3]);
    or4[1] = make_float4(y[4], y[5], y[6],  y[7]);
    or4[2] = make_float4(y[8], y[9], y[10], y[11]);
}

extern "C" void kernel_launch(void* const* d_in, const int* in_sizes, int n_in,
                              void* d_out, int out_size, void* d_ws, size_t ws_size,
                              hipStream_t stream)
{
    const float* x    = (const float*)d_in[0];
    const float* wi   = (const float*)d_in[1];   // in_proj_w [36,12]
    const float* bi   = (const float*)d_in[2];   // in_proj_b [36]
    const float* wo   = (const float*)d_in[3];   // out_proj_w [12,12]
    const float* bo   = (const float*)d_in[4];   // out_proj_b [12]
    const float* tha  = (const float*)d_in[5];   // attn_theta [12]
    const float* w1   = (const float*)d_in[6];   // lin1_w [12,12]
    const float* b1   = (const float*)d_in[7];   // lin1_b [12]
    const float* thf  = (const float*)d_in[8];   // ffn_theta [12]
    const float* w2   = (const float*)d_in[9];   // lin2_w [12,12]
    const float* b2   = (const float*)d_in[10];  // lin2_b [12]
    const float* g1   = (const float*)d_in[11];  // ln1_g
    const float* be1  = (const float*)d_in[12];  // ln1_b
    const float* g2   = (const float*)d_in[13];  // ln2_g
    const float* be2  = (const float*)d_in[14];  // ln2_b
    const int*   mask = (const int*)d_in[15];    // mask [8,256]
    float* out = (float*)d_out;
    float4* part = (float4*)d_ws;                // [B*T, H, KSPLIT] = 512 KB

    attn_partial_kernel<<<BB * HH * KSPLIT, TT, 0, stream>>>(x, wi, bi, mask, part);
    fused_tail_kernel<<<(BB * TT + 63) / 64, 64, 0, stream>>>(
        x, part, wo, bo, tha, w1, b1, thf, w2, b2, g1, be1, g2, be2, out);
}